// Round 2
// baseline (921.568 us; speedup 1.0000x reference)
//
#include <hip/hip_runtime.h>
#include <hip/hip_cooperative_groups.h>

namespace cg = cooperative_groups;

#define KVOX 12000
#define TPTS 35
#define FIN  7
#define DD   10
#define HH   400
#define WW   352
#define CO   128
#define EPSBN 1e-3f
#define NCELL (DD * HH * WW)              // 1,408,000 cells
#define TOTALF4 ((size_t)NCELL * 32)      // 45,056,000 float4s = 720.9 MB

// cooperative geometry: MUST be fully co-resident (grid.sync).
// __launch_bounds__(256,4) forces <=128 VGPR -> 4 blocks/CU -> 1024 blocks
// co-resident >= CGRID. LDS 13.7KB -> 11 blocks/CU (not binding).
#define CGRID 1000
#define NWAVE (CGRID * 4)                 // 4000 wave-slots
#define VPW   (KVOX / NWAVE)              // 3 voxels per wave (exact)
#define F4PT  (TOTALF4 / ((size_t)CGRID * 256))  // 176 float4 per thread (exact)

static_assert(KVOX % NWAVE == 0, "uniform voxels per wave");
static_assert(TOTALF4 % ((size_t)CGRID * 256) == 0, "uniform fill per thread");

// fallback geometry (round-1 verified path)
#define FILLB 2048
#define CB    3000
static_assert(CB * 4 == KVOX, "fallback grid covers voxels exactly");

// ---------------------------------------------------------------------------
// Cooperative single-kernel: zero-fill out, compute VFE into regs (overlapped
// with the store drain), grid-sync, then direct atomicAdd scatter.
// Timed floor here = harness poison (~461us, invariant) + 720.9MB write
// (~118us) + ~18MB reads/atomics (hidden). No __syncthreads anywhere: all LDS
// dependencies are intra-wave (lanes of one wave write, same wave reads) and
// the compiler orders them with lgkmcnt.
// ---------------------------------------------------------------------------
__global__ __launch_bounds__(256, 4) void vfe_coop(
    const float* __restrict__ feat,
    const float* __restrict__ w1, const float* __restrict__ b1,
    const float* __restrict__ g1, const float* __restrict__ be1,
    const float* __restrict__ m1, const float* __restrict__ v1,
    const float* __restrict__ w2, const float* __restrict__ b2,
    const float* __restrict__ g2, const float* __restrict__ be2,
    const float* __restrict__ m2, const float* __restrict__ v2,
    const int* __restrict__ coord,
    float* __restrict__ out)
{
    const int tid   = threadIdx.x;
    const int wv    = tid >> 6;            // wave in block: 0..3
    const int lane  = tid & 63;
    const int wslot = blockIdx.x * 4 + wv; // 0..3999

    __shared__ __align__(16) float sxp[4][TPTS][8];    // padded point features
    __shared__ __align__(16) float spwm[4][TPTS][16];  // masked stage-1 pointwise
    __shared__ __align__(16) float sagg[4][16];        // stage-1 aggregate

    // ---- phase 1a: issue the zero-fill stores (fire-and-forget) ----
    {
        const float4 z = make_float4(0.f, 0.f, 0.f, 0.f);
        float4* o4 = (float4*)out;
        const size_t base = (size_t)blockIdx.x * 256 + tid;
        #pragma unroll 8
        for (int i = 0; i < (int)F4PT; ++i)
            o4[base + (size_t)i * (CGRID * 256)] = z;
    }

    // ---- phase 1b: compute VPW voxels into registers (overlaps store drain) ----
    float resA[VPW], resB[VPW];
    int   locs[VPW];

    for (int it = 0; it < VPW; ++it) {
        const int k = wslot + it * NWAVE;
        const float* fk = feat + (size_t)k * (TPTS * FIN);

        // stage features into LDS, rows padded to 8 (b128 broadcast reads later)
        for (int i = lane; i < TPTS * FIN; i += 64)
            sxp[wv][i / FIN][i % FIN] = fk[i];
        if (lane < TPTS) sxp[wv][lane][FIN] = 0.0f;

        // per-point mask straight from global (L2-hot)
        bool pred = false;
        if (lane < TPTS) {
            const float* row = fk + lane * FIN;
            float mx = row[0];
            #pragma unroll
            for (int f = 1; f < FIN; ++f) mx = fmaxf(mx, row[f]);
            pred = (mx != 0.0f);
        }
        const unsigned long long bal = __ballot(pred);
        const int nvalid = __popcll(bal);

        // stage 1: dense(7->16)+relu+BN on lanes u<16; agg over ALL t
        if (lane < 16) {
            const int u = lane;
            float w1c[8];
            #pragma unroll
            for (int f = 0; f < FIN; ++f) w1c[f] = w1[f * 16 + u];
            w1c[FIN] = 0.0f;
            const float b     = b1[u];
            const float scale = g1[u] * rsqrtf(v1[u] + EPSBN);
            const float shift = be1[u] - m1[u] * scale;

            float agg = -INFINITY;
            float pw[TPTS];
            #pragma unroll
            for (int t = 0; t < TPTS; ++t) {
                const float4 xa = *(const float4*)&sxp[wv][t][0];
                const float4 xb = *(const float4*)&sxp[wv][t][4];
                float d = b;
                d = fmaf(xa.x, w1c[0], d); d = fmaf(xa.y, w1c[1], d);
                d = fmaf(xa.z, w1c[2], d); d = fmaf(xa.w, w1c[3], d);
                d = fmaf(xb.x, w1c[4], d); d = fmaf(xb.y, w1c[5], d);
                d = fmaf(xb.z, w1c[6], d); d = fmaf(xb.w, w1c[7], d);
                d = fmaxf(d, 0.0f);
                const float p = fmaf(d, scale, shift);
                agg = fmaxf(agg, p);
                pw[t] = p;
            }
            sagg[wv][u] = agg;
            #pragma unroll
            for (int t = 0; t < TPTS; ++t) {
                const float mk = ((bal >> t) & 1ULL) ? 1.0f : 0.0f;
                spwm[wv][t][u] = pw[t] * mk;   // banks (t*16+u)%32: conflict-free
            }
        }

        // stage 2: dense(32->64)+relu+BN, channel v per lane, agg factorized
        {
            const int v = lane;
            float w2c[32];
            #pragma unroll
            for (int u = 0; u < 32; ++u) w2c[u] = w2[u * 64 + v];
            const float b     = b2[v];
            const float scale = g2[v] * rsqrtf(v2[v] + EPSBN);
            const float shift = be2[v] - m2[v] * scale;

            float aggdot = 0.0f;
            {
                const float4* ar = (const float4*)&sagg[wv][0];
                #pragma unroll
                for (int q = 0; q < 4; ++q) {
                    const float4 a = ar[q];
                    aggdot = fmaf(a.x, w2c[16 + 4 * q + 0], aggdot);
                    aggdot = fmaf(a.y, w2c[16 + 4 * q + 1], aggdot);
                    aggdot = fmaf(a.z, w2c[16 + 4 * q + 2], aggdot);
                    aggdot = fmaf(a.w, w2c[16 + 4 * q + 3], aggdot);
                }
            }

            float aggAll = -INFINITY;
            float voxA   = -INFINITY;
            #pragma unroll 7
            for (int t = 0; t < TPTS; ++t) {
                const float mk = ((bal >> t) & 1ULL) ? 1.0f : 0.0f;
                const float4* xr = (const float4*)&spwm[wv][t][0];
                float d = fmaf(mk, aggdot, b);
                #pragma unroll
                for (int q = 0; q < 4; ++q) {
                    const float4 xv = xr[q];
                    d = fmaf(xv.x, w2c[4 * q + 0], d);
                    d = fmaf(xv.y, w2c[4 * q + 1], d);
                    d = fmaf(xv.z, w2c[4 * q + 2], d);
                    d = fmaf(xv.w, w2c[4 * q + 3], d);
                }
                d = fmaxf(d, 0.0f);
                const float p = fmaf(d, scale, shift);
                aggAll = fmaxf(aggAll, p);
                voxA   = fmaxf(voxA, p * mk);
            }
            float voxB;
            if (nvalid == 0)          voxB = 0.0f;
            else if (nvalid < TPTS)   voxB = fmaxf(aggAll, 0.0f);
            else                      voxB = aggAll;

            const int4 c = ((const int4*)coord)[k];
            locs[it] = (((c.x * DD + c.y) * HH + c.z) * WW + c.w);
            resA[it] = voxA;
            resB[it] = voxB;
        }
    }

    // ---- grid-wide barrier: all zero-fill stores visible ----
    cg::this_grid().sync();

    // ---- phase 2: direct scatter (tf.scatter_nd duplicates accumulate) ----
    #pragma unroll
    for (int it = 0; it < VPW; ++it) {
        float* o = out + (size_t)locs[it] * CO;
        atomicAdd(o + lane,      resA[it]);
        atomicAdd(o + 64 + lane, resB[it]);
    }
}

// ---------------------------------------------------------------------------
// Fallback path (round-1 harness-verified, 791us): plain fill + compute/scatter
// ---------------------------------------------------------------------------
__global__ __launch_bounds__(256) void fill_out(float4* __restrict__ o4)
{
    const float4 z = make_float4(0.f, 0.f, 0.f, 0.f);
    const size_t stride = (size_t)FILLB * 256;
    for (size_t i = (size_t)blockIdx.x * 256 + threadIdx.x; i < TOTALF4; i += stride)
        o4[i] = z;
}

__global__ __launch_bounds__(256) void vfe_scatter(
    const float* __restrict__ feat,
    const float* __restrict__ w1, const float* __restrict__ b1,
    const float* __restrict__ g1, const float* __restrict__ be1,
    const float* __restrict__ m1, const float* __restrict__ v1,
    const float* __restrict__ w2, const float* __restrict__ b2,
    const float* __restrict__ g2, const float* __restrict__ be2,
    const float* __restrict__ m2, const float* __restrict__ v2,
    const int* __restrict__ coord,
    float* __restrict__ out)
{
    const int tid  = threadIdx.x;
    const int wv   = tid >> 6;
    const int lane = tid & 63;
    const int k    = blockIdx.x * 4 + wv;

    __shared__ __align__(16) float sxp[4][TPTS][8];
    __shared__ __align__(16) float spwm[4][TPTS][16];
    __shared__ __align__(16) float sagg[4][16];

    const float* fk = feat + (size_t)k * (TPTS * FIN);

    for (int i = lane; i < TPTS * FIN; i += 64)
        sxp[wv][i / FIN][i % FIN] = fk[i];
    if (lane < TPTS) sxp[wv][lane][FIN] = 0.0f;

    bool pred = false;
    if (lane < TPTS) {
        const float* row = fk + lane * FIN;
        float mx = row[0];
        #pragma unroll
        for (int f = 1; f < FIN; ++f) mx = fmaxf(mx, row[f]);
        pred = (mx != 0.0f);
    }
    const unsigned long long bal = __ballot(pred);
    const int nvalid = __popcll(bal);
    __syncthreads();

    if (lane < 16) {
        const int u = lane;
        float w1c[8];
        #pragma unroll
        for (int f = 0; f < FIN; ++f) w1c[f] = w1[f * 16 + u];
        w1c[FIN] = 0.0f;
        const float b     = b1[u];
        const float scale = g1[u] * rsqrtf(v1[u] + EPSBN);
        const float shift = be1[u] - m1[u] * scale;

        float agg = -INFINITY;
        float pw[TPTS];
        #pragma unroll
        for (int t = 0; t < TPTS; ++t) {
            const float4 xa = *(const float4*)&sxp[wv][t][0];
            const float4 xb = *(const float4*)&sxp[wv][t][4];
            float d = b;
            d = fmaf(xa.x, w1c[0], d); d = fmaf(xa.y, w1c[1], d);
            d = fmaf(xa.z, w1c[2], d); d = fmaf(xa.w, w1c[3], d);
            d = fmaf(xb.x, w1c[4], d); d = fmaf(xb.y, w1c[5], d);
            d = fmaf(xb.z, w1c[6], d); d = fmaf(xb.w, w1c[7], d);
            d = fmaxf(d, 0.0f);
            const float p = fmaf(d, scale, shift);
            agg = fmaxf(agg, p);
            pw[t] = p;
        }
        sagg[wv][u] = agg;
        #pragma unroll
        for (int t = 0; t < TPTS; ++t) {
            const float mk = ((bal >> t) & 1ULL) ? 1.0f : 0.0f;
            spwm[wv][t][u] = pw[t] * mk;
        }
    }
    __syncthreads();

    {
        const int v = lane;
        float w2c[32];
        #pragma unroll
        for (int u = 0; u < 32; ++u) w2c[u] = w2[u * 64 + v];
        const float b     = b2[v];
        const float scale = g2[v] * rsqrtf(v2[v] + EPSBN);
        const float shift = be2[v] - m2[v] * scale;

        float aggdot = 0.0f;
        {
            const float4* ar = (const float4*)&sagg[wv][0];
            #pragma unroll
            for (int q = 0; q < 4; ++q) {
                const float4 a = ar[q];
                aggdot = fmaf(a.x, w2c[16 + 4 * q + 0], aggdot);
                aggdot = fmaf(a.y, w2c[16 + 4 * q + 1], aggdot);
                aggdot = fmaf(a.z, w2c[16 + 4 * q + 2], aggdot);
                aggdot = fmaf(a.w, w2c[16 + 4 * q + 3], aggdot);
            }
        }

        float aggAll = -INFINITY;
        float voxA   = -INFINITY;
        #pragma unroll 7
        for (int t = 0; t < TPTS; ++t) {
            const float mk = ((bal >> t) & 1ULL) ? 1.0f : 0.0f;
            const float4* xr = (const float4*)&spwm[wv][t][0];
            float d = fmaf(mk, aggdot, b);
            #pragma unroll
            for (int q = 0; q < 4; ++q) {
                const float4 xv = xr[q];
                d = fmaf(xv.x, w2c[4 * q + 0], d);
                d = fmaf(xv.y, w2c[4 * q + 1], d);
                d = fmaf(xv.z, w2c[4 * q + 2], d);
                d = fmaf(xv.w, w2c[4 * q + 3], d);
            }
            d = fmaxf(d, 0.0f);
            const float p = fmaf(d, scale, shift);
            aggAll = fmaxf(aggAll, p);
            voxA   = fmaxf(voxA, p * mk);
        }
        float voxB;
        if (nvalid == 0)          voxB = 0.0f;
        else if (nvalid < TPTS)   voxB = fmaxf(aggAll, 0.0f);
        else                      voxB = aggAll;

        const int4 c = ((const int4*)coord)[k];
        const int loc = (((c.x * DD + c.y) * HH + c.z) * WW + c.w);
        float* o = out + (size_t)loc * CO;
        atomicAdd(o + v,      voxA);
        atomicAdd(o + 64 + v, voxB);
    }
}

extern "C" void kernel_launch(void* const* d_in, const int* in_sizes, int n_in,
                              void* d_out, int out_size, void* d_ws, size_t ws_size,
                              hipStream_t stream) {
    const float* feat = (const float*)d_in[0];
    const float* w1   = (const float*)d_in[1];
    const float* b1   = (const float*)d_in[2];
    const float* g1   = (const float*)d_in[3];
    const float* be1  = (const float*)d_in[4];
    const float* m1   = (const float*)d_in[5];
    const float* v1   = (const float*)d_in[6];
    const float* v1g  = nullptr; (void)v1g;
    const float* w2   = (const float*)d_in[7];
    const float* b2   = (const float*)d_in[8];
    const float* g2   = (const float*)d_in[9];
    const float* be2  = (const float*)d_in[10];
    const float* m2   = (const float*)d_in[11];
    const float* v2   = (const float*)d_in[12];
    const int*   coord = (const int*)d_in[13];
    float* out = (float*)d_out;

    void* args[] = {
        (void*)&feat,
        (void*)&w1, (void*)&b1, (void*)&g1, (void*)&be1, (void*)&m1, (void*)&v1,
        (void*)&w2, (void*)&b2, (void*)&g2, (void*)&be2, (void*)&m2, (void*)&v2,
        (void*)&coord, (void*)&out
    };
    hipError_t err = hipLaunchCooperativeKernel((const void*)vfe_coop,
                                                dim3(CGRID), dim3(256),
                                                args, 0, stream);
    if (err != hipSuccess) {
        // round-1 verified fallback: serial fill + compute/scatter
        fill_out<<<FILLB, 256, 0, stream>>>((float4*)out);
        vfe_scatter<<<CB, 256, 0, stream>>>(feat, w1, b1, g1, be1, m1, v1,
                                            w2, b2, g2, be2, m2, v2, coord, out);
    }
}

// Round 3
// 773.018 us; speedup vs baseline: 1.1922x; 1.1922x over previous
//
#include <hip/hip_runtime.h>

#define KVOX 12000
#define TPTS 35
#define FIN  7
#define DD   10
#define HH   400
#define WW   352
#define CO   128
#define EPSBN 1e-3f
#define NCELL (DD * HH * WW)              // 1,408,000 cells
#define TOTALF4 ((size_t)NCELL * 32)      // 45,056,000 float4 = 720.9 MB
#define MULTI 0xFFFFFFFFu
#define MARKB ((size_t)NCELL * 4)         // 5,632,000 B  (<= known ws >= 6,144,000)
#define MARKF4 (NCELL / 4)                // 352,000 float4

#define CLRB  512                         // clear grid
#define CB    3000                        // 4 waves/block -> 1 voxel/wave
#define WRB   2048                        // background-writer grid
#define FILLB 2048                        // fallback fill grid

static_assert(CB * 4 == KVOX, "grid covers voxels exactly");
static_assert(NCELL % 4 == 0, "mark region float4-clearable");

// ---------------------------------------------------------------------------
// Shared per-wave VFE pipeline (harness-verified math, rounds 0-2, passed).
// NO __syncthreads: every LDS dependency is intra-wave (this wave writes its
// own [wv] slice, same wave reads it) — compiler orders via lgkmcnt. This
// makes it callable under wave-divergent conditions (dupfix early-exit).
// ---------------------------------------------------------------------------
__device__ __forceinline__ void vfe_wave(
    int k, int wv, int lane,
    const float* __restrict__ feat,
    const float* __restrict__ w1, const float* __restrict__ b1,
    const float* __restrict__ g1, const float* __restrict__ be1,
    const float* __restrict__ m1, const float* __restrict__ v1,
    const float* __restrict__ w2, const float* __restrict__ b2,
    const float* __restrict__ g2, const float* __restrict__ be2,
    const float* __restrict__ m2, const float* __restrict__ v2,
    float (&sxp)[TPTS][8], float (&spwm)[TPTS][16], float (&sagg)[16],
    float& voxA_out, float& voxB_out)
{
    const float* fk = feat + (size_t)k * (TPTS * FIN);

    // stage features into LDS, rows padded to 8 (b128 broadcast reads later)
    for (int i = lane; i < TPTS * FIN; i += 64)
        sxp[i / FIN][i % FIN] = fk[i];
    if (lane < TPTS) sxp[lane][FIN] = 0.0f;

    // per-point mask straight from global (L2-hot)
    bool pred = false;
    if (lane < TPTS) {
        const float* row = fk + lane * FIN;
        float mx = row[0];
        #pragma unroll
        for (int f = 1; f < FIN; ++f) mx = fmaxf(mx, row[f]);
        pred = (mx != 0.0f);
    }
    const unsigned long long bal = __ballot(pred);
    const int nvalid = __popcll(bal);

    // stage 1: dense(7->16)+relu+BN on lanes u<16; agg over ALL t; masked store
    if (lane < 16) {
        const int u = lane;
        float w1c[8];
        #pragma unroll
        for (int f = 0; f < FIN; ++f) w1c[f] = w1[f * 16 + u];
        w1c[FIN] = 0.0f;
        const float b     = b1[u];
        const float scale = g1[u] * rsqrtf(v1[u] + EPSBN);
        const float shift = be1[u] - m1[u] * scale;

        float agg = -INFINITY;
        float pw[TPTS];
        #pragma unroll
        for (int t = 0; t < TPTS; ++t) {
            const float4 xa = *(const float4*)&sxp[t][0];
            const float4 xb = *(const float4*)&sxp[t][4];
            float d = b;
            d = fmaf(xa.x, w1c[0], d); d = fmaf(xa.y, w1c[1], d);
            d = fmaf(xa.z, w1c[2], d); d = fmaf(xa.w, w1c[3], d);
            d = fmaf(xb.x, w1c[4], d); d = fmaf(xb.y, w1c[5], d);
            d = fmaf(xb.z, w1c[6], d); d = fmaf(xb.w, w1c[7], d);
            d = fmaxf(d, 0.0f);
            const float p = fmaf(d, scale, shift);
            agg = fmaxf(agg, p);
            pw[t] = p;
        }
        sagg[u] = agg;
        #pragma unroll
        for (int t = 0; t < TPTS; ++t) {
            const float mk = ((bal >> t) & 1ULL) ? 1.0f : 0.0f;
            spwm[t][u] = pw[t] * mk;     // banks (t*16+u)%32: conflict-free
        }
    }

    // stage 2: dense(32->64)+relu+BN, channel v per lane, agg-term factorized
    const int v = lane;
    float w2c[32];
    #pragma unroll
    for (int u = 0; u < 32; ++u) w2c[u] = w2[u * 64 + v];
    const float b     = b2[v];
    const float scale = g2[v] * rsqrtf(v2[v] + EPSBN);
    const float shift = be2[v] - m2[v] * scale;

    float aggdot = 0.0f;
    {
        const float4* ar = (const float4*)&sagg[0];
        #pragma unroll
        for (int q = 0; q < 4; ++q) {
            const float4 a = ar[q];
            aggdot = fmaf(a.x, w2c[16 + 4 * q + 0], aggdot);
            aggdot = fmaf(a.y, w2c[16 + 4 * q + 1], aggdot);
            aggdot = fmaf(a.z, w2c[16 + 4 * q + 2], aggdot);
            aggdot = fmaf(a.w, w2c[16 + 4 * q + 3], aggdot);
        }
    }

    float aggAll = -INFINITY;
    float voxA   = -INFINITY;
    #pragma unroll 7
    for (int t = 0; t < TPTS; ++t) {
        const float mk = ((bal >> t) & 1ULL) ? 1.0f : 0.0f;
        const float4* xr = (const float4*)&spwm[t][0];
        float d = fmaf(mk, aggdot, b);
        #pragma unroll
        for (int q = 0; q < 4; ++q) {
            const float4 xv = xr[q];
            d = fmaf(xv.x, w2c[4 * q + 0], d);
            d = fmaf(xv.y, w2c[4 * q + 1], d);
            d = fmaf(xv.z, w2c[4 * q + 2], d);
            d = fmaf(xv.w, w2c[4 * q + 3], d);
        }
        d = fmaxf(d, 0.0f);
        const float p = fmaf(d, scale, shift);
        aggAll = fmaxf(aggAll, p);
        voxA   = fmaxf(voxA, p * mk);
    }
    float voxB;
    if (nvalid == 0)          voxB = 0.0f;
    else if (nvalid < TPTS)   voxB = fmaxf(aggAll, 0.0f);
    else                      voxB = aggAll;

    voxA_out = voxA;
    voxB_out = voxB;
}

// ---- 1) clear the mark array (ws may be poisoned) ----
__global__ __launch_bounds__(256) void clear_marks(float4* __restrict__ m4)
{
    const float4 z = make_float4(0.f, 0.f, 0.f, 0.f);
    const int stride = CLRB * 256;
    for (int i = blockIdx.x * 256 + threadIdx.x; i < MARKF4; i += stride)
        m4[i] = z;
}

// ---- 2) compute + claim: winner writes its 512B row DIRECTLY into out ----
// mark[cell]: 0 = untouched, k+1 = single voxel k, MULTI = >=2 voxels.
__global__ __launch_bounds__(256) void vfe_claim(
    const float* __restrict__ feat,
    const float* __restrict__ w1, const float* __restrict__ b1,
    const float* __restrict__ g1, const float* __restrict__ be1,
    const float* __restrict__ m1, const float* __restrict__ v1,
    const float* __restrict__ w2, const float* __restrict__ b2,
    const float* __restrict__ g2, const float* __restrict__ be2,
    const float* __restrict__ m2, const float* __restrict__ v2,
    const int* __restrict__ coord,
    unsigned* __restrict__ mark,
    float* __restrict__ out)
{
    const int tid  = threadIdx.x;
    const int wv   = tid >> 6;
    const int lane = tid & 63;
    const int k    = blockIdx.x * 4 + wv;

    __shared__ __align__(16) float sxp[4][TPTS][8];
    __shared__ __align__(16) float spwm[4][TPTS][16];
    __shared__ __align__(16) float sagg[4][16];

    float voxA, voxB;
    vfe_wave(k, wv, lane, feat, w1, b1, g1, be1, m1, v1,
             w2, b2, g2, be2, m2, v2,
             sxp[wv], spwm[wv], sagg[wv], voxA, voxB);

    const int4 c = ((const int4*)coord)[k];
    const int loc = (((c.x * DD + c.y) * HH + c.z) * WW + c.w);

    int won = 0;
    if (lane == 0) {
        const unsigned old = atomicCAS(mark + loc, 0u, (unsigned)(k + 1));
        if (old != 0u) atomicExch(mark + loc, MULTI);   // demote to multi
        won = (old == 0u);
    }
    won = __shfl(won, 0);
    if (won) {
        float* o = out + (size_t)loc * CO;
        o[lane]      = voxA;
        o[64 + lane] = voxB;
    }
}

// ---- 3) background writer: zero every cell that is NOT single-claimed ----
// Single full write of out (the floor). Claimed rows are already in place.
__global__ __launch_bounds__(256) void write_bg(
    const unsigned* __restrict__ mark, float4* __restrict__ out4)
{
    const float4 z = make_float4(0.f, 0.f, 0.f, 0.f);
    const size_t stride = (size_t)WRB * 256;
    for (size_t i = (size_t)blockIdx.x * 256 + threadIdx.x; i < TOTALF4; i += stride) {
        const unsigned m = mark[i >> 5];          // 32 threads/cell -> L1 broadcast
        if ((m == 0u) | (m == MULTI)) out4[i] = z;
    }
}

// ---- 4) duplicate fix: recompute voxels in MULTI cells, atomicAdd ----
// Expected ~50 cells of 12000 voxels; nearly every wave exits after one load.
__global__ __launch_bounds__(256) void vfe_dupfix(
    const float* __restrict__ feat,
    const float* __restrict__ w1, const float* __restrict__ b1,
    const float* __restrict__ g1, const float* __restrict__ be1,
    const float* __restrict__ m1, const float* __restrict__ v1,
    const float* __restrict__ w2, const float* __restrict__ b2,
    const float* __restrict__ g2, const float* __restrict__ be2,
    const float* __restrict__ m2, const float* __restrict__ v2,
    const int* __restrict__ coord,
    const unsigned* __restrict__ mark,
    float* __restrict__ out)
{
    const int tid  = threadIdx.x;
    const int wv   = tid >> 6;
    const int lane = tid & 63;
    const int k    = blockIdx.x * 4 + wv;

    __shared__ __align__(16) float sxp[4][TPTS][8];
    __shared__ __align__(16) float spwm[4][TPTS][16];
    __shared__ __align__(16) float sagg[4][16];

    const int4 c = ((const int4*)coord)[k];
    const int loc = (((c.x * DD + c.y) * HH + c.z) * WW + c.w);
    if (mark[loc] != MULTI) return;               // wave-uniform exit

    float voxA, voxB;
    vfe_wave(k, wv, lane, feat, w1, b1, g1, be1, m1, v1,
             w2, b2, g2, be2, m2, v2,
             sxp[wv], spwm[wv], sagg[wv], voxA, voxB);

    float* o = out + (size_t)loc * CO;
    atomicAdd(o + lane,      voxA);
    atomicAdd(o + 64 + lane, voxB);
}

// ---------------------------------------------------------------------------
// Fallback (only if ws < 5.63MB — round-0 evidence says ws >= 6.14MB, so this
// should never run): round-1 verified fill + compute/atomic-scatter.
// ---------------------------------------------------------------------------
__global__ __launch_bounds__(256) void fill_out(float4* __restrict__ o4)
{
    const float4 z = make_float4(0.f, 0.f, 0.f, 0.f);
    const size_t stride = (size_t)FILLB * 256;
    for (size_t i = (size_t)blockIdx.x * 256 + threadIdx.x; i < TOTALF4; i += stride)
        o4[i] = z;
}

__global__ __launch_bounds__(256) void vfe_scatter(
    const float* __restrict__ feat,
    const float* __restrict__ w1, const float* __restrict__ b1,
    const float* __restrict__ g1, const float* __restrict__ be1,
    const float* __restrict__ m1, const float* __restrict__ v1,
    const float* __restrict__ w2, const float* __restrict__ b2,
    const float* __restrict__ g2, const float* __restrict__ be2,
    const float* __restrict__ m2, const float* __restrict__ v2,
    const int* __restrict__ coord,
    float* __restrict__ out)
{
    const int tid  = threadIdx.x;
    const int wv   = tid >> 6;
    const int lane = tid & 63;
    const int k    = blockIdx.x * 4 + wv;

    __shared__ __align__(16) float sxp[4][TPTS][8];
    __shared__ __align__(16) float spwm[4][TPTS][16];
    __shared__ __align__(16) float sagg[4][16];

    float voxA, voxB;
    vfe_wave(k, wv, lane, feat, w1, b1, g1, be1, m1, v1,
             w2, b2, g2, be2, m2, v2,
             sxp[wv], spwm[wv], sagg[wv], voxA, voxB);

    const int4 c = ((const int4*)coord)[k];
    const int loc = (((c.x * DD + c.y) * HH + c.z) * WW + c.w);
    float* o = out + (size_t)loc * CO;
    atomicAdd(o + lane,      voxA);
    atomicAdd(o + 64 + lane, voxB);
}

extern "C" void kernel_launch(void* const* d_in, const int* in_sizes, int n_in,
                              void* d_out, int out_size, void* d_ws, size_t ws_size,
                              hipStream_t stream) {
    const float* feat = (const float*)d_in[0];
    const float* w1   = (const float*)d_in[1];
    const float* b1   = (const float*)d_in[2];
    const float* g1   = (const float*)d_in[3];
    const float* be1  = (const float*)d_in[4];
    const float* m1   = (const float*)d_in[5];
    const float* v1   = (const float*)d_in[6];
    const float* w2   = (const float*)d_in[7];
    const float* b2   = (const float*)d_in[8];
    const float* g2   = (const float*)d_in[9];
    const float* be2  = (const float*)d_in[10];
    const float* m2   = (const float*)d_in[11];
    const float* v2   = (const float*)d_in[12];
    const int*   coord = (const int*)d_in[13];
    float* out = (float*)d_out;

    if (ws_size >= MARKB) {
        unsigned* mark = (unsigned*)d_ws;
        clear_marks<<<CLRB, 256, 0, stream>>>((float4*)d_ws);
        vfe_claim<<<CB, 256, 0, stream>>>(feat, w1, b1, g1, be1, m1, v1,
                                          w2, b2, g2, be2, m2, v2,
                                          coord, mark, out);
        write_bg<<<WRB, 256, 0, stream>>>(mark, (float4*)out);
        vfe_dupfix<<<CB, 256, 0, stream>>>(feat, w1, b1, g1, be1, m1, v1,
                                           w2, b2, g2, be2, m2, v2,
                                           coord, mark, out);
    } else {
        fill_out<<<FILLB, 256, 0, stream>>>((float4*)out);
        vfe_scatter<<<CB, 256, 0, stream>>>(feat, w1, b1, g1, be1, m1, v1,
                                            w2, b2, g2, be2, m2, v2, coord, out);
    }
}